// Round 4
// baseline (600.383 us; speedup 1.0000x reference)
//
#include <hip/hip_runtime.h>
#include <hip/hip_bf16.h>
#include <cfloat>
#include <cmath>

#define HIDDEN  4096
#define EXPERTS 64
#define TOPK    8
#define BM      64            // tokens per block
#define BK      64            // K-chunk
#define XP      66            // x-tile LDS pitch (floats): keeps float2 reads 8B-aligned,
                              // staging scalar stores only 4-way bank-conflicted (cheap)
#define NCHUNK  (HIDDEN / BK)

// ---------------------------------------------------------------------------
// Pre-kernel: W[64][4096] -> Wt[4096][64] so the main kernel's W stage is
// fully coalesced. 1 MB total, negligible cost, re-done every launch (d_ws is
// re-poisoned by the harness).
// ---------------------------------------------------------------------------
__global__ __launch_bounds__(256) void transpose_w_kernel(
    const float* __restrict__ W, float* __restrict__ Wt) {
  int t  = blockIdx.x * 256 + threadIdx.x;   // 0 .. 65535
  int e  = t >> 10;                          // expert 0..63
  int kq = t & 1023;                         // float4 index along k
  float4 v = reinterpret_cast<const float4*>(W)[e * (HIDDEN / 4) + kq];
  int k = kq << 2;
  Wt[(size_t)(k + 0) * EXPERTS + e] = v.x;
  Wt[(size_t)(k + 1) * EXPERTS + e] = v.y;
  Wt[(size_t)(k + 2) * EXPERTS + e] = v.z;
  Wt[(size_t)(k + 3) * EXPERTS + e] = v.w;
}

// ---------------------------------------------------------------------------
// Fused router: GEMM (fp32 VALU, chunked-Kahan accumulation) + top-8 + renorm
// ---------------------------------------------------------------------------
__global__ __launch_bounds__(256) void router_kernel(
    const float* __restrict__ x, const float* __restrict__ Wt,
    const float* __restrict__ bias_g, float* __restrict__ out, int T) {
  __shared__ float xs[BK][XP];       // transposed x tile: xs[k][token]
  __shared__ float ws[BK][EXPERTS];  // Wt tile: ws[k][expert]

  const int tid  = threadIdx.x;
  const int tx   = tid & 15;   // expert group: experts 4*tx .. 4*tx+3
  const int ty   = tid >> 4;   // token group : tokens  4*ty .. 4*ty+3
  const int tok0 = blockIdx.x * BM;

  const int sr = tid >> 4;     // staging row base (row = sr + 16*i)
  const int sc = tid & 15;     // staging float4 column

  // bias for this thread's 4 experts
  float bias[4];
#pragma unroll
  for (int j = 0; j < 4; ++j) bias[j] = bias_g[4 * tx + j];

  // Kahan totals
  float tot[4][4], comp[4][4];
#pragma unroll
  for (int i = 0; i < 4; ++i)
#pragma unroll
    for (int j = 0; j < 4; ++j) { tot[i][j] = 0.f; comp[i][j] = 0.f; }

  // register prefetch of chunk 0 (T14: issue-early / write-late)
  float4 xr[4], wr[4];
#pragma unroll
  for (int i = 0; i < 4; ++i) {
    int r = sr + 16 * i;
    xr[i] = *reinterpret_cast<const float4*>(
        x + (size_t)(tok0 + r) * HIDDEN + 4 * sc);
    wr[i] = *reinterpret_cast<const float4*>(
        Wt + (size_t)r * EXPERTS + 4 * sc);
  }

  for (int c = 0; c < NCHUNK; ++c) {
    __syncthreads();  // previous compute done -> LDS reusable
#pragma unroll
    for (int i = 0; i < 4; ++i) {
      int r = sr + 16 * i;
      // x transpose-store: 4 scalars, stride-XP rows (4-way conflict, rare)
      xs[4 * sc + 0][r] = xr[i].x;
      xs[4 * sc + 1][r] = xr[i].y;
      xs[4 * sc + 2][r] = xr[i].z;
      xs[4 * sc + 3][r] = xr[i].w;
      // W stage: contiguous float4
      *reinterpret_cast<float4*>(&ws[r][4 * sc]) = wr[i];
    }
    __syncthreads();

    // prefetch next chunk while computing this one
    if (c + 1 < NCHUNK) {
      const int kk0 = (c + 1) * BK;
#pragma unroll
      for (int i = 0; i < 4; ++i) {
        int r = sr + 16 * i;
        xr[i] = *reinterpret_cast<const float4*>(
            x + (size_t)(tok0 + r) * HIDDEN + kk0 + 4 * sc);
        wr[i] = *reinterpret_cast<const float4*>(
            Wt + (size_t)(kk0 + r) * EXPERTS + 4 * sc);
      }
    }

    // ---- inner product over this chunk (fp32 FMAs) ----
    float acc[4][4];
#pragma unroll
    for (int i = 0; i < 4; ++i)
#pragma unroll
      for (int j = 0; j < 4; ++j) acc[i][j] = 0.f;

#pragma unroll 8
    for (int kk = 0; kk < BK; ++kk) {
      float2 xa = *reinterpret_cast<const float2*>(&xs[kk][4 * ty]);
      float2 xb = *reinterpret_cast<const float2*>(&xs[kk][4 * ty + 2]);
      float4 wv = *reinterpret_cast<const float4*>(&ws[kk][4 * tx]);
      const float xv[4] = {xa.x, xa.y, xb.x, xb.y};
#pragma unroll
      for (int i = 0; i < 4; ++i) {
        acc[i][0] += xv[i] * wv.x;
        acc[i][1] += xv[i] * wv.y;
        acc[i][2] += xv[i] * wv.z;
        acc[i][3] += xv[i] * wv.w;
      }
    }

    // fold chunk into Kahan totals (no fast-math: preserved)
#pragma unroll
    for (int i = 0; i < 4; ++i)
#pragma unroll
      for (int j = 0; j < 4; ++j) {
        float y  = acc[i][j] - comp[i][j];
        float t2 = tot[i][j] + y;
        comp[i][j] = (t2 - tot[i][j]) - y;
        tot[i][j]  = t2;
      }
  }

  // ---- epilogue: logits -> LDS, per-token top-8 ----
  __syncthreads();
  float* lg = &xs[0][0];  // reuse xs as logits[64][XP]
#pragma unroll
  for (int i = 0; i < 4; ++i)
#pragma unroll
    for (int j = 0; j < 4; ++j)
      lg[(size_t)(4 * ty + i) * XP + 4 * tx + j] = tot[i][j] + bias[j];
  __syncthreads();

  if (tid < BM) {
    const float* row = lg + (size_t)tid * XP;
    float sv[TOPK];
    int   si[TOPK];
#pragma unroll
    for (int j = 0; j < TOPK; ++j) { sv[j] = -FLT_MAX; si[j] = 0; }

    for (int e = 0; e < EXPERTS; ++e) {
      float v = row[e];
      if (v > sv[TOPK - 1]) {          // strict > : stable ties (lower idx first)
        sv[TOPK - 1] = v;
        si[TOPK - 1] = e;
#pragma unroll
        for (int j = TOPK - 1; j >= 1; --j) {
          if (sv[j] > sv[j - 1]) {     // strict > keeps equal keys in index order
            float tv = sv[j]; sv[j] = sv[j - 1]; sv[j - 1] = tv;
            int   ti = si[j]; si[j] = si[j - 1]; si[j - 1] = ti;
          }
        }
      }
    }

    // softmax over top-8 only (global denominator cancels after renorm)
    const float m0 = sv[0];
    float w[TOPK], s = 0.f;
#pragma unroll
    for (int j = 0; j < TOPK; ++j) { w[j] = expf(sv[j] - m0); s += w[j]; }

    const int t = tok0 + tid;
#pragma unroll
    for (int j = 0; j < TOPK; ++j) out[(size_t)t * TOPK + j] = w[j] / s;
#pragma unroll
    for (int j = 0; j < TOPK; ++j)
      out[(size_t)T * TOPK + (size_t)t * TOPK + j] = (float)si[j];
  }
}

extern "C" void kernel_launch(void* const* d_in, const int* in_sizes, int n_in,
                              void* d_out, int out_size, void* d_ws, size_t ws_size,
                              hipStream_t stream) {
  const float* x = (const float*)d_in[0];
  const float* W = (const float*)d_in[1];
  const float* b = (const float*)d_in[2];
  float* out = (float*)d_out;
  float* Wt  = (float*)d_ws;  // 4096*64*4 = 1 MB scratch

  const int T = in_sizes[0] / HIDDEN;  // 16384

  hipLaunchKernelGGL(transpose_w_kernel, dim3((EXPERTS * HIDDEN / 4) / 256),
                     dim3(256), 0, stream, W, Wt);
  hipLaunchKernelGGL(router_kernel, dim3(T / BM), dim3(256), 0, stream,
                     x, Wt, b, out, T);
}

// Round 5
// 470.909 us; speedup vs baseline: 1.2749x; 1.2749x over previous
//
#include <hip/hip_runtime.h>
#include <hip/hip_bf16.h>
#include <cfloat>
#include <cmath>

#define HIDDEN  4096
#define EXPERTS 64
#define TOPK    8
#define BM      64            // tokens per block tile
#define BK      64            // K-chunk staged in LDS
#define XP      66            // x-tile LDS pitch: float2 reads stay 8B-aligned,
                              // staging stores only 4-way conflicted (~3% cycles)

// ---------------------------------------------------------------------------
// Pre-kernel: W[64][4096] -> Wt[4096][64] for coalesced staging.
// ---------------------------------------------------------------------------
__global__ __launch_bounds__(256) void transpose_w_kernel(
    const float* __restrict__ W, float* __restrict__ Wt) {
  int t  = blockIdx.x * 256 + threadIdx.x;   // 0 .. 65535
  int e  = t >> 10;                          // expert 0..63
  int kq = t & 1023;                         // float4 index along k
  float4 v = reinterpret_cast<const float4*>(W)[e * (HIDDEN / 4) + kq];
  int k = kq << 2;
  Wt[(size_t)(k + 0) * EXPERTS + e] = v.x;
  Wt[(size_t)(k + 1) * EXPERTS + e] = v.y;
  Wt[(size_t)(k + 2) * EXPERTS + e] = v.z;
  Wt[(size_t)(k + 3) * EXPERTS + e] = v.w;
}

// ---------------------------------------------------------------------------
// Split-K GEMM partial: block (tile, kz) computes x[tile, kz-slice] @ Wt.
// grid (T/BM, KS). 4 blocks/CU -> 16 waves/CU (was 1 block/CU: latency-bound).
// Deterministic: no atomics; partials summed in fixed order by top8_kernel.
// ---------------------------------------------------------------------------
__global__ __launch_bounds__(256) void router_partial_kernel(
    const float* __restrict__ x, const float* __restrict__ Wt,
    float* __restrict__ part, int T, int klen) {
  __shared__ float xs[BK][XP];       // transposed x tile: xs[k][token]
  __shared__ float ws[BK][EXPERTS];  // Wt tile: ws[k][expert]

  const int tid   = threadIdx.x;
  const int tx    = tid & 15;        // expert group: 4*tx .. 4*tx+3
  const int ty    = tid >> 4;        // token group : 4*ty .. 4*ty+3
  const int tok0  = blockIdx.x * BM;
  const int kz    = blockIdx.y;
  const int kbase = kz * klen;
  const int nchunk = klen / BK;

  const int sr = tid >> 4;           // staging row base
  const int sc = tid & 15;           // staging float4 column

  float tot[4][4], comp[4][4];
#pragma unroll
  for (int i = 0; i < 4; ++i)
#pragma unroll
    for (int j = 0; j < 4; ++j) { tot[i][j] = 0.f; comp[i][j] = 0.f; }

  // register prefetch of first chunk (issue-early / write-late)
  float4 xr[4], wr[4];
#pragma unroll
  for (int i = 0; i < 4; ++i) {
    int r = sr + 16 * i;
    xr[i] = *reinterpret_cast<const float4*>(
        x + (size_t)(tok0 + r) * HIDDEN + kbase + 4 * sc);
    wr[i] = *reinterpret_cast<const float4*>(
        Wt + (size_t)(kbase + r) * EXPERTS + 4 * sc);
  }

  for (int c = 0; c < nchunk; ++c) {
    __syncthreads();
#pragma unroll
    for (int i = 0; i < 4; ++i) {
      int r = sr + 16 * i;
      xs[4 * sc + 0][r] = xr[i].x;
      xs[4 * sc + 1][r] = xr[i].y;
      xs[4 * sc + 2][r] = xr[i].z;
      xs[4 * sc + 3][r] = xr[i].w;
      *reinterpret_cast<float4*>(&ws[r][4 * sc]) = wr[i];
    }
    __syncthreads();

    if (c + 1 < nchunk) {
      const int kk0 = kbase + (c + 1) * BK;
#pragma unroll
      for (int i = 0; i < 4; ++i) {
        int r = sr + 16 * i;
        xr[i] = *reinterpret_cast<const float4*>(
            x + (size_t)(tok0 + r) * HIDDEN + kk0 + 4 * sc);
        wr[i] = *reinterpret_cast<const float4*>(
            Wt + (size_t)(kk0 + r) * EXPERTS + 4 * sc);
      }
    }

    float acc[4][4];
#pragma unroll
    for (int i = 0; i < 4; ++i)
#pragma unroll
      for (int j = 0; j < 4; ++j) acc[i][j] = 0.f;

#pragma unroll 8
    for (int kk = 0; kk < BK; ++kk) {
      float2 xa = *reinterpret_cast<const float2*>(&xs[kk][4 * ty]);
      float2 xb = *reinterpret_cast<const float2*>(&xs[kk][4 * ty + 2]);
      float4 wv = *reinterpret_cast<const float4*>(&ws[kk][4 * tx]);
      const float xv[4] = {xa.x, xa.y, xb.x, xb.y};
#pragma unroll
      for (int i = 0; i < 4; ++i) {
        acc[i][0] += xv[i] * wv.x;
        acc[i][1] += xv[i] * wv.y;
        acc[i][2] += xv[i] * wv.z;
        acc[i][3] += xv[i] * wv.w;
      }
    }

    // Kahan fold: keeps per-partial logit error ~3e-7 so top-8 order matches ref
#pragma unroll
    for (int i = 0; i < 4; ++i)
#pragma unroll
      for (int j = 0; j < 4; ++j) {
        float y  = acc[i][j] - comp[i][j];
        float t2 = tot[i][j] + y;
        comp[i][j] = (t2 - tot[i][j]) - y;
        tot[i][j]  = t2;
      }
  }

  // write partials directly from registers (float4, coalesced per 16-lane row)
  const size_t base = ((size_t)kz * T + tok0) * EXPERTS;
#pragma unroll
  for (int i = 0; i < 4; ++i) {
    float4 v = make_float4(tot[i][0], tot[i][1], tot[i][2], tot[i][3]);
    *reinterpret_cast<float4*>(
        &part[base + (size_t)(4 * ty + i) * EXPERTS + 4 * tx]) = v;
  }
}

// ---------------------------------------------------------------------------
// Reduce KS partials + bias (fixed order -> deterministic), top-8, renorm.
// One thread per token; insertion sort fully unrolled (no scratch arrays).
// ---------------------------------------------------------------------------
__global__ __launch_bounds__(256) void top8_kernel(
    const float* __restrict__ part, const float* __restrict__ bias_g,
    float* __restrict__ out, int T, int KS) {
  const int t = blockIdx.x * 256 + threadIdx.x;

  float sv[TOPK];
  int   si[TOPK];
#pragma unroll
  for (int j = 0; j < TOPK; ++j) { sv[j] = -FLT_MAX; si[j] = 0; }

#pragma unroll
  for (int e4 = 0; e4 < EXPERTS / 4; ++e4) {
    float4 a = *reinterpret_cast<const float4*>(&bias_g[4 * e4]);
    for (int kz = 0; kz < KS; ++kz) {
      float4 p = *reinterpret_cast<const float4*>(
          &part[((size_t)kz * T + t) * EXPERTS + 4 * e4]);
      a.x += p.x; a.y += p.y; a.z += p.z; a.w += p.w;
    }
    const float vv[4] = {a.x, a.y, a.z, a.w};
#pragma unroll
    for (int jj = 0; jj < 4; ++jj) {
      const float v = vv[jj];
      const int   e = 4 * e4 + jj;        // ascending e: stable ties like lax.top_k
      if (v > sv[TOPK - 1]) {
        sv[TOPK - 1] = v; si[TOPK - 1] = e;
#pragma unroll
        for (int j = TOPK - 1; j >= 1; --j) {
          if (sv[j] > sv[j - 1]) {        // strict > keeps equal keys index-ordered
            float tv = sv[j]; sv[j] = sv[j - 1]; sv[j - 1] = tv;
            int   ti = si[j]; si[j] = si[j - 1]; si[j - 1] = ti;
          }
        }
      }
    }
  }

  const float m0 = sv[0];
  float w[TOPK], s = 0.f;
#pragma unroll
  for (int j = 0; j < TOPK; ++j) { w[j] = expf(sv[j] - m0); s += w[j]; }

#pragma unroll
  for (int j = 0; j < TOPK; ++j) out[(size_t)t * TOPK + j] = w[j] / s;
#pragma unroll
  for (int j = 0; j < TOPK; ++j)
    out[(size_t)T * TOPK + (size_t)t * TOPK + j] = (float)si[j];
}

// ---------------------------------------------------------------------------
// Fallback fused kernel (used only if ws_size can't hold split-K partials).
// ---------------------------------------------------------------------------
__global__ __launch_bounds__(256) void router_fused_kernel(
    const float* __restrict__ x, const float* __restrict__ Wt,
    const float* __restrict__ bias_g, float* __restrict__ out, int T) {
  __shared__ float xs[BK][XP];
  __shared__ float ws[BK][EXPERTS];
  const int tid  = threadIdx.x;
  const int tx   = tid & 15;
  const int ty   = tid >> 4;
  const int tok0 = blockIdx.x * BM;
  const int sr = tid >> 4, sc = tid & 15;

  float bias[4];
#pragma unroll
  for (int j = 0; j < 4; ++j) bias[j] = bias_g[4 * tx + j];

  float tot[4][4], comp[4][4];
#pragma unroll
  for (int i = 0; i < 4; ++i)
#pragma unroll
    for (int j = 0; j < 4; ++j) { tot[i][j] = 0.f; comp[i][j] = 0.f; }

  float4 xr[4], wr[4];
#pragma unroll
  for (int i = 0; i < 4; ++i) {
    int r = sr + 16 * i;
    xr[i] = *reinterpret_cast<const float4*>(x + (size_t)(tok0 + r) * HIDDEN + 4 * sc);
    wr[i] = *reinterpret_cast<const float4*>(Wt + (size_t)r * EXPERTS + 4 * sc);
  }

  for (int c = 0; c < HIDDEN / BK; ++c) {
    __syncthreads();
#pragma unroll
    for (int i = 0; i < 4; ++i) {
      int r = sr + 16 * i;
      xs[4 * sc + 0][r] = xr[i].x;
      xs[4 * sc + 1][r] = xr[i].y;
      xs[4 * sc + 2][r] = xr[i].z;
      xs[4 * sc + 3][r] = xr[i].w;
      *reinterpret_cast<float4*>(&ws[r][4 * sc]) = wr[i];
    }
    __syncthreads();
    if (c + 1 < HIDDEN / BK) {
      const int kk0 = (c + 1) * BK;
#pragma unroll
      for (int i = 0; i < 4; ++i) {
        int r = sr + 16 * i;
        xr[i] = *reinterpret_cast<const float4*>(x + (size_t)(tok0 + r) * HIDDEN + kk0 + 4 * sc);
        wr[i] = *reinterpret_cast<const float4*>(Wt + (size_t)(kk0 + r) * EXPERTS + 4 * sc);
      }
    }
    float acc[4][4];
#pragma unroll
    for (int i = 0; i < 4; ++i)
#pragma unroll
      for (int j = 0; j < 4; ++j) acc[i][j] = 0.f;
#pragma unroll 8
    for (int kk = 0; kk < BK; ++kk) {
      float2 xa = *reinterpret_cast<const float2*>(&xs[kk][4 * ty]);
      float2 xb = *reinterpret_cast<const float2*>(&xs[kk][4 * ty + 2]);
      float4 wv = *reinterpret_cast<const float4*>(&ws[kk][4 * tx]);
      const float xv[4] = {xa.x, xa.y, xb.x, xb.y};
#pragma unroll
      for (int i = 0; i < 4; ++i) {
        acc[i][0] += xv[i] * wv.x;
        acc[i][1] += xv[i] * wv.y;
        acc[i][2] += xv[i] * wv.z;
        acc[i][3] += xv[i] * wv.w;
      }
    }
#pragma unroll
    for (int i = 0; i < 4; ++i)
#pragma unroll
      for (int j = 0; j < 4; ++j) {
        float y  = acc[i][j] - comp[i][j];
        float t2 = tot[i][j] + y;
        comp[i][j] = (t2 - tot[i][j]) - y;
        tot[i][j]  = t2;
      }
  }

  __syncthreads();
  float* lg = &xs[0][0];
#pragma unroll
  for (int i = 0; i < 4; ++i)
#pragma unroll
    for (int j = 0; j < 4; ++j)
      lg[(size_t)(4 * ty + i) * XP + 4 * tx + j] = tot[i][j] + bias[j];
  __syncthreads();

  if (tid < BM) {
    const float* row = lg + (size_t)tid * XP;
    float sv[TOPK]; int si[TOPK];
#pragma unroll
    for (int j = 0; j < TOPK; ++j) { sv[j] = -FLT_MAX; si[j] = 0; }
#pragma unroll
    for (int e = 0; e < EXPERTS; ++e) {
      float v = row[e];
      if (v > sv[TOPK - 1]) {
        sv[TOPK - 1] = v; si[TOPK - 1] = e;
#pragma unroll
        for (int j = TOPK - 1; j >= 1; --j) {
          if (sv[j] > sv[j - 1]) {
            float tv = sv[j]; sv[j] = sv[j - 1]; sv[j - 1] = tv;
            int   ti = si[j]; si[j] = si[j - 1]; si[j - 1] = ti;
          }
        }
      }
    }
    const float m0 = sv[0];
    float w[TOPK], s = 0.f;
#pragma unroll
    for (int j = 0; j < TOPK; ++j) { w[j] = expf(sv[j] - m0); s += w[j]; }
    const int t = tok0 + tid;
#pragma unroll
    for (int j = 0; j < TOPK; ++j) out[(size_t)t * TOPK + j] = w[j] / s;
#pragma unroll
    for (int j = 0; j < TOPK; ++j)
      out[(size_t)T * TOPK + (size_t)t * TOPK + j] = (float)si[j];
  }
}

extern "C" void kernel_launch(void* const* d_in, const int* in_sizes, int n_in,
                              void* d_out, int out_size, void* d_ws, size_t ws_size,
                              hipStream_t stream) {
  const float* x = (const float*)d_in[0];
  const float* W = (const float*)d_in[1];
  const float* b = (const float*)d_in[2];
  float* out = (float*)d_out;

  const int T = in_sizes[0] / HIDDEN;  // 16384

  float* Wt   = (float*)d_ws;                          // 1 MB
  float* part = (float*)d_ws + (size_t)EXPERTS * HIDDEN;

  const size_t wt_bytes   = (size_t)EXPERTS * HIDDEN * 4;
  const size_t part_bytes = (size_t)T * EXPERTS * 4;   // per K-slice (4 MB)

  int KS = 0;
  if (ws_size >= wt_bytes + 4 * part_bytes) KS = 4;        // 17 MB
  else if (ws_size >= wt_bytes + 2 * part_bytes) KS = 2;   // 9 MB
  else if (ws_size >= wt_bytes + 1 * part_bytes) KS = 1;   // 5 MB

  hipLaunchKernelGGL(transpose_w_kernel, dim3((EXPERTS * HIDDEN / 4) / 256),
                     dim3(256), 0, stream, W, Wt);

  if (KS > 0) {
    const int klen = HIDDEN / KS;
    hipLaunchKernelGGL(router_partial_kernel, dim3(T / BM, KS), dim3(256), 0,
                       stream, x, Wt, part, T, klen);
    hipLaunchKernelGGL(top8_kernel, dim3(T / 256), dim3(256), 0, stream,
                       part, b, out, T, KS);
  } else {
    hipLaunchKernelGGL(router_fused_kernel, dim3(T / BM), dim3(256), 0, stream,
                       x, Wt, b, out, T);
  }
}

// Round 11
// 461.696 us; speedup vs baseline: 1.3004x; 1.0200x over previous
//
#include <hip/hip_runtime.h>
#include <hip/hip_bf16.h>
#include <cfloat>
#include <cmath>

#define HIDDEN  4096
#define EXPERTS 64
#define TOPK    8
#define BM      128           // tokens per block tile
#define BK      32            // K-chunk staged in LDS (double-buffered)
#define XP      132           // x-tile pitch (floats): 528B rows = 16B-aligned for b128;
                              // ty-groups land on disjoint bank quads (broadcast-friendly)

// ---------------------------------------------------------------------------
// Pre-kernel: W[64][4096] -> Wt[4096][64] for coalesced staging.
// ---------------------------------------------------------------------------
__global__ __launch_bounds__(256) void transpose_w_kernel(
    const float* __restrict__ W, float* __restrict__ Wt) {
  int t  = blockIdx.x * 256 + threadIdx.x;   // 0 .. 65535
  int e  = t >> 10;                          // expert 0..63
  int kq = t & 1023;                         // float4 index along k
  float4 v = reinterpret_cast<const float4*>(W)[e * (HIDDEN / 4) + kq];
  int k = kq << 2;
  Wt[(size_t)(k + 0) * EXPERTS + e] = v.x;
  Wt[(size_t)(k + 1) * EXPERTS + e] = v.y;
  Wt[(size_t)(k + 2) * EXPERTS + e] = v.z;
  Wt[(size_t)(k + 3) * EXPERTS + e] = v.w;
}

// ---------------------------------------------------------------------------
// Split-K GEMM partial, 8x4 register tile.
//  - x LDS reads are 16-lane broadcasts (addr depends on ty only) -> ~0.19 B
//    effective LDS per lane-FMA: LDS off the critical path.
//  - pipeline: stage(c) -> barrier -> issue(c+1) -> compute(c). Loads are
//    issued AFTER the barrier so the compiler's vmcnt(0)-before-s_barrier
//    drains nothing (the round-5 stall). One barrier per chunk.
//  - chunk-fold accumulation: 32-long inner chains folded into tot[] ->
//    logit error ~1.5e-7, preserving top-8 index fidelity vs the reference.
// ---------------------------------------------------------------------------
__global__ __launch_bounds__(256) void router_partial_kernel(
    const float* __restrict__ x, const float* __restrict__ Wt,
    float* __restrict__ part, int T, int klen) {
  __shared__ float xs[2][BK][XP];       // 2 x 32 x 132 x 4B = 33792 B
  __shared__ float ws[2][BK][EXPERTS];  // 2 x 32 x  64 x 4B = 16384 B

  const int tid   = threadIdx.x;
  const int tx    = tid & 15;        // expert group: experts 4tx..4tx+3
  const int ty    = tid >> 4;        // token group : tokens 8ty..8ty+7
  const int tok0  = blockIdx.x * BM;
  const int kz    = blockIdx.y;
  const int kbase = kz * klen;
  const int nchunk = klen / BK;

  // staging maps
  const int xrg = tid >> 3;          // 0..31: x row base (rows xrg + 32i)
  const int xc8 = tid & 7;           // 0..7 : float4 col within 32-k chunk
  const int wr  = tid >> 3;          // 0..31: w row
  const int wc  = tid & 7;           // 0..7 : float4 col (+8p)

  float4 xr[4];
  float4 wv2[2];

  float tot[8][4];
#pragma unroll
  for (int i = 0; i < 8; ++i)
#pragma unroll
    for (int j = 0; j < 4; ++j) tot[i][j] = 0.f;

  // ---- issue chunk-0 loads ----
  {
    const int kc = kbase;
#pragma unroll
    for (int i = 0; i < 4; ++i)
      xr[i] = *reinterpret_cast<const float4*>(
          x + (size_t)(tok0 + xrg + 32 * i) * HIDDEN + kc + 4 * xc8);
#pragma unroll
    for (int p = 0; p < 2; ++p)
      wv2[p] = *reinterpret_cast<const float4*>(
          Wt + (size_t)(kc + wr) * EXPERTS + 4 * (wc + 8 * p));
  }

  for (int c = 0; c < nchunk; ++c) {
    const int b = c & 1;

    // ---- stage chunk c (consumes prefetch regs; vmcnt waits happen here) ----
#pragma unroll
    for (int i = 0; i < 4; ++i) {
      xs[b][4 * xc8 + 0][xrg + 32 * i] = xr[i].x;
      xs[b][4 * xc8 + 1][xrg + 32 * i] = xr[i].y;
      xs[b][4 * xc8 + 2][xrg + 32 * i] = xr[i].z;
      xs[b][4 * xc8 + 3][xrg + 32 * i] = xr[i].w;
    }
#pragma unroll
    for (int p = 0; p < 2; ++p)
      *reinterpret_cast<float4*>(&ws[b][wr][4 * (wc + 8 * p)]) = wv2[p];

    __syncthreads();   // nothing in flight -> no vmcnt drain cost

    // ---- issue chunk c+1 AFTER the barrier (lands during compute) ----
    if (c + 1 < nchunk) {
      const int kc = kbase + (c + 1) * BK;
#pragma unroll
      for (int i = 0; i < 4; ++i)
        xr[i] = *reinterpret_cast<const float4*>(
            x + (size_t)(tok0 + xrg + 32 * i) * HIDDEN + kc + 4 * xc8);
#pragma unroll
      for (int p = 0; p < 2; ++p)
        wv2[p] = *reinterpret_cast<const float4*>(
            Wt + (size_t)(kc + wr) * EXPERTS + 4 * (wc + 8 * p));
    }

    // ---- compute chunk c: 32 kk x (8 tok x 4 exp) FMAs ----
    float acc[8][4];
#pragma unroll
    for (int i = 0; i < 8; ++i)
#pragma unroll
      for (int j = 0; j < 4; ++j) acc[i][j] = 0.f;

#pragma unroll 8
    for (int kk = 0; kk < BK; ++kk) {
      float4 xa = *reinterpret_cast<const float4*>(&xs[b][kk][8 * ty]);
      float4 xb = *reinterpret_cast<const float4*>(&xs[b][kk][8 * ty + 4]);
      float4 wv = *reinterpret_cast<const float4*>(&ws[b][kk][4 * tx]);
      const float xv[8] = {xa.x, xa.y, xa.z, xa.w, xb.x, xb.y, xb.z, xb.w};
#pragma unroll
      for (int i = 0; i < 8; ++i) {
        acc[i][0] += xv[i] * wv.x;
        acc[i][1] += xv[i] * wv.y;
        acc[i][2] += xv[i] * wv.z;
        acc[i][3] += xv[i] * wv.w;
      }
    }

    // fold chunk into totals (balanced partials -> ~1.5e-7 logit error)
#pragma unroll
    for (int i = 0; i < 8; ++i)
#pragma unroll
      for (int j = 0; j < 4; ++j) tot[i][j] += acc[i][j];
  }

  // ---- write partials (float4, coalesced within each 16-lane tx row) ----
  const size_t base = ((size_t)kz * T + tok0) * EXPERTS;
#pragma unroll
  for (int i = 0; i < 8; ++i) {
    float4 v = make_float4(tot[i][0], tot[i][1], tot[i][2], tot[i][3]);
    *reinterpret_cast<float4*>(
        &part[base + (size_t)(8 * ty + i) * EXPERTS + 4 * tx]) = v;
  }
}

// ---------------------------------------------------------------------------
// Reduce KS partials + bias (fixed order -> deterministic), top-8, renorm.
// ---------------------------------------------------------------------------
__global__ __launch_bounds__(256) void top8_kernel(
    const float* __restrict__ part, const float* __restrict__ bias_g,
    float* __restrict__ out, int T, int KS) {
  const int t = blockIdx.x * 256 + threadIdx.x;

  float sv[TOPK];
  int   si[TOPK];
#pragma unroll
  for (int j = 0; j < TOPK; ++j) { sv[j] = -FLT_MAX; si[j] = 0; }

#pragma unroll
  for (int e4 = 0; e4 < EXPERTS / 4; ++e4) {
    float4 a = *reinterpret_cast<const float4*>(&bias_g[4 * e4]);
    for (int kz = 0; kz < KS; ++kz) {
      float4 p = *reinterpret_cast<const float4*>(
          &part[((size_t)kz * T + t) * EXPERTS + 4 * e4]);
      a.x += p.x; a.y += p.y; a.z += p.z; a.w += p.w;
    }
    const float vv[4] = {a.x, a.y, a.z, a.w};
#pragma unroll
    for (int jj = 0; jj < 4; ++jj) {
      const float v = vv[jj];
      const int   e = 4 * e4 + jj;        // ascending e: stable ties like lax.top_k
      if (v > sv[TOPK - 1]) {
        sv[TOPK - 1] = v; si[TOPK - 1] = e;
#pragma unroll
        for (int j = TOPK - 1; j >= 1; --j) {
          if (sv[j] > sv[j - 1]) {        // strict > keeps equal keys index-ordered
            float tv = sv[j]; sv[j] = sv[j - 1]; sv[j - 1] = tv;
            int   ti = si[j]; si[j] = si[j - 1]; si[j - 1] = ti;
          }
        }
      }
    }
  }

  const float m0 = sv[0];
  float w[TOPK], s = 0.f;
#pragma unroll
  for (int j = 0; j < TOPK; ++j) { w[j] = expf(sv[j] - m0); s += w[j]; }

#pragma unroll
  for (int j = 0; j < TOPK; ++j) out[(size_t)t * TOPK + j] = w[j] / s;
#pragma unroll
  for (int j = 0; j < TOPK; ++j)
    out[(size_t)T * TOPK + (size_t)t * TOPK + j] = (float)si[j];
}

extern "C" void kernel_launch(void* const* d_in, const int* in_sizes, int n_in,
                              void* d_out, int out_size, void* d_ws, size_t ws_size,
                              hipStream_t stream) {
  const float* x = (const float*)d_in[0];
  const float* W = (const float*)d_in[1];
  const float* b = (const float*)d_in[2];
  float* out = (float*)d_out;

  const int T = in_sizes[0] / HIDDEN;  // 16384

  float* Wt   = (float*)d_ws;                          // 1 MB
  float* part = (float*)d_ws + (size_t)EXPERTS * HIDDEN;

  const size_t wt_bytes   = (size_t)EXPERTS * HIDDEN * 4;
  const size_t part_bytes = (size_t)T * EXPERTS * 4;   // 4 MB per K-slice

  int KS = 1;
  if (ws_size >= wt_bytes + 8 * part_bytes) KS = 8;        // ~34 MB
  else if (ws_size >= wt_bytes + 4 * part_bytes) KS = 4;   // ~17 MB (proven fits)
  else if (ws_size >= wt_bytes + 2 * part_bytes) KS = 2;

  const int klen = HIDDEN / KS;

  hipLaunchKernelGGL(transpose_w_kernel, dim3((EXPERTS * HIDDEN / 4) / 256),
                     dim3(256), 0, stream, W, Wt);
  hipLaunchKernelGGL(router_partial_kernel, dim3(T / BM, KS), dim3(256), 0,
                     stream, x, Wt, part, T, klen);
  hipLaunchKernelGGL(top8_kernel, dim3(T / 256), dim3(256), 0, stream,
                     part, b, out, T, KS);
}